// Round 11
// baseline (236.025 us; speedup 1.0000x reference)
//
#include <hip/hip_runtime.h>

// Problem: MyStrategicModel_35691178229867
// R10 post-mortem: scalar ILP didn't beat pk (197 vs 190) — execution/power
// bound, not issue bound. Sustained clock drops with arithmetic density
// (R4: 1.50 GHz -> R8: 1.31 GHz): power-limited regime.
// R11: R8's pk block-4 structure (best known), NS=4 = two independent v2
// chains/thread. Bitwise-identical per-sample math to R8. Discriminates
// stall-limited (-> ~172 us) vs clock-limited (-> ~190+ us). If neutral/worse,
// declare roofline.

#define XLO -10.0f
#define XHI 10.0f
#define NC 2   // two v2 chains = 4 samples/thread

typedef float v2 __attribute__((ext_vector_type(2)));

__device__ __forceinline__ v2 fma2(v2 a, v2 b, v2 c) {
    return __builtin_elementwise_fma(a, b, c);
}

__device__ __forceinline__ float clampx(float x) {
    return fminf(fmaxf(x, XLO), XHI);   // v_med3_f32
}

__device__ __forceinline__ v2 clamp2(v2 x) {
    v2 r;
    r.x = clampx(x.x);
    r.y = clampx(x.y);
    return r;
}

__device__ __forceinline__ float rsq_nr(float t) {
    float y = __builtin_amdgcn_rsqf(t);
    float c = __builtin_fmaf(-0.5f * (t * y), y, 1.5f);
    return y * c;
}

struct P {
    v2 w0s, w1s, v0s, v1s, bm1s, hw0s, hw1s;
    v2 mvr[NC];
};

// nblocks blocks of 4 PGA steps per chain; gc refreshed per block, pre-folded
// into kink-branch constants. Kink test + clip exact per step. NC independent
// chains interleaved for ILP.
__device__ __forceinline__ void solve(int nblocks,
                                      const v2* sx0, const v2* sx1,
                                      const v2* e0, const v2* e1,
                                      const v2* e0k, const v2* e1k,
                                      const P& p, v2* ox0, v2* ox1) {
    const v2 c95 = 0.95f, one = 1.0f;
    v2 x0[NC], x1[NC];
#pragma unroll
    for (int n = 0; n < NC; ++n) { x0[n] = sx0[n]; x1[n] = sx1[n]; }
    for (int k = 0; k < nblocks; ++k) {
        v2 f0[NC], f0k[NC], f1[NC], f1k[NC];
#pragma unroll
        for (int n = 0; n < NC; ++n) {
            v2 tau = fma2(x0[n], p.w0s, fma2(x1[n], p.w1s, p.bm1s));
            v2 t2 = fma2(tau, tau, one);
            v2 rq;
            rq.x = __builtin_amdgcn_rsqf(t2.x);
            rq.y = __builtin_amdgcn_rsqf(t2.y);
            v2 gc = tau * rq;
            f0[n]  = fma2(-gc, p.hw0s, e0[n]);
            f0k[n] = fma2(-gc, p.hw0s, e0k[n]);
            f1[n]  = fma2(-gc, p.hw1s, e1[n]);
            f1k[n] = fma2(-gc, p.hw1s, e1k[n]);
        }
#pragma unroll
        for (int h = 0; h < 4; ++h) {
#pragma unroll
            for (int n = 0; n < NC; ++n) {
                v2 q = fma2(x0[n], p.v0s, fma2(x1[n], p.v1s, p.mvr[n]));
                v2 a0, a1;
                a0.x = (q.x > 0.0f) ? f0k[n].x : f0[n].x;
                a0.y = (q.y > 0.0f) ? f0k[n].y : f0[n].y;
                a1.x = (q.x > 0.0f) ? f1k[n].x : f1[n].x;
                a1.y = (q.y > 0.0f) ? f1k[n].y : f1[n].y;
                x0[n] = clamp2(fma2(c95, x0[n], a0));
                x1[n] = clamp2(fma2(c95, x1[n], a1));
            }
        }
    }
#pragma unroll
    for (int n = 0; n < NC; ++n) { ox0[n] = x0[n]; ox1[n] = x1[n]; }
}

__global__ __launch_bounds__(256, 8)
void strategic_kernel(const float* __restrict__ X,
                      const float* __restrict__ wp,
                      const float* __restrict__ bp,
                      const float* __restrict__ vp,
                      float* __restrict__ out, int B4) {
    int i = blockIdx.x * blockDim.x + threadIdx.x;
    if (i >= B4) return;

    const float w0 = wp[0], w1 = wp[1], b = bp[0], v0 = vp[0], v1 = vp[1];

    P p;
    p.w0s = w0; p.w1s = w1; p.v0s = v0; p.v1s = v1;
    p.bm1s = b - 1.0f;
    p.hw0s = 0.5f * w0; p.hw1s = 0.5f * w1;
    const v2 bp1s = b + 1.0f;
    const v2 k0s = 0.475f * v0, k1s = 0.475f * v1;   // COST*(1-EPS)*v
    const v2 one = 1.0f, half = 0.5f, c05 = 0.05f;

    // Chain n handles samples from float4 load at [i + n*B4] (coalesced).
    v2 r0[NC], r1[NC];
    v2 sx0[NC], sx1[NC], p5r0[NC], p5r1[NC];
    v2 xt0[NC], xt1[NC];
    v2 fc_p1[NC], fc_p2[NC];
    v2 e0[NC], e1[NC], e0k[NC], e1k[NC];

#pragma unroll
    for (int n = 0; n < NC; ++n) {
        float4 r4 = reinterpret_cast<const float4*>(X)[i + n * B4];
        r0[n].x = r4.x; r0[n].y = r4.z;   // coord 0 of both samples
        r1[n].x = r4.y; r1[n].y = r4.w;   // coord 1 of both samples
        sx0[n] = clamp2(r0[n]);
        sx1[n] = clamp2(r1[n]);
        p.mvr[n].x = -(__builtin_fmaf(r1[n].x, v1, r0[n].x * v0));
        p.mvr[n].y = -(__builtin_fmaf(r1[n].y, v1, r0[n].y * v0));
        p5r0[n] = c05 * r0[n];
        p5r1[n] = c05 * r1[n];
        xt0[n] = r0[n];
        xt1[n] = r1[n];
        fc_p1[n] = __builtin_nanf("");   // NaN never compares equal
        fc_p2[n] = __builtin_nanf("");
    }

    int c = 0;
    for (; c < 11; ++c) {
        // fder at xt (NR-refined rsq; 11 calls, cheap)
        v2 fc[NC];
        bool per1 = true, per2 = true;
#pragma unroll
        for (int n = 0; n < NC; ++n) {
            v2 sp = fma2(xt0[n], p.w0s, fma2(xt1[n], p.w1s, bp1s));
            v2 tt = fma2(sp, sp, one);
            v2 rs;
            rs.x = rsq_nr(tt.x);
            rs.y = rsq_nr(tt.y);
            fc[n] = half * sp * rs;
            e0[n] = fma2(fc[n], p.w0s, p5r0[n]);
            e1[n] = fma2(fc[n], p.w1s, p5r1[n]);
            e0k[n] = e0[n] - k0s;
            e1k[n] = e1[n] - k1s;
            per1 = per1 && (fc[n].x == fc_p1[n].x) && (fc[n].y == fc_p1[n].y);
            per2 = per2 && (fc[n].x == fc_p2[n].x) && (fc[n].y == fc_p2[n].y);
        }

        if (__all(per1) || (__all(per2) && ((10 - c) & 1))) break;
#pragma unroll
        for (int n = 0; n < NC; ++n) {
            fc_p2[n] = fc_p1[n];
            fc_p1[n] = fc[n];
        }

        solve(25, sx0, sx1, e0, e1, e0k, e1k, p, xt0, xt1);  // 100 steps
    }

    if (c == 11) {   // natural exhaust: e-consts are fd(S_9); refresh at S_10
#pragma unroll
        for (int n = 0; n < NC; ++n) {
            v2 sp = fma2(xt0[n], p.w0s, fma2(xt1[n], p.w1s, bp1s));
            v2 tt = fma2(sp, sp, one);
            v2 rs;
            rs.x = rsq_nr(tt.x);
            rs.y = rsq_nr(tt.y);
            v2 fc = half * sp * rs;
            e0[n] = fma2(fc, p.w0s, p5r0[n]);
            e1[n] = fma2(fc, p.w1s, p5r1[n]);
            e0k[n] = e0[n] - k0s;
            e1k[n] = e1[n] - k1s;
        }
    }

    // Final (differentiable) solve: 200 steps = 50 blocks
    v2 x0[NC], x1[NC];
    solve(50, sx0, sx1, e0, e1, e0k, e1k, p, x0, x1);

    const v2 bs = b;
#pragma unroll
    for (int n = 0; n < NC; ++n) {
        v2 res = fma2(x0[n], p.w0s, fma2(x1[n], p.w1s, bs));
        float2 o;
        o.x = res.x;
        o.y = res.y;
        reinterpret_cast<float2*>(out)[i + n * B4] = o;
    }
}

extern "C" void kernel_launch(void* const* d_in, const int* in_sizes, int n_in,
                              void* d_out, int out_size, void* d_ws, size_t ws_size,
                              hipStream_t stream) {
    const float* X = (const float*)d_in[0];
    const float* w = (const float*)d_in[1];
    const float* b = (const float*)d_in[2];
    const float* v = (const float*)d_in[3];
    float* out = (float*)d_out;

    int B = in_sizes[0] / 2;   // X is [B, 2]
    int B4 = B / 4;            // 4 samples per thread (2 v2 chains)
    int block = 256;
    int grid = (B4 + block - 1) / block;
    strategic_kernel<<<grid, block, 0, stream>>>(X, w, b, v, out, B4);
}

// Round 12
// 222.632 us; speedup vs baseline: 1.0602x; 1.0602x over previous
//
#include <hip/hip_runtime.h>

// Problem: MyStrategicModel_35691178229867
// R12 = revert to R8 (best known: 190 us dispatch / 222 us bench).
// Session verdict: execution/power-limited at the ~1.3 GHz sustained clock.
//  - per-step kink+clip-exact core at its op floor (9 ops/sample-step)
//  - gc staleness cliff between 3-stale (bitwise-neutral) and 9-stale (fails)
//  - scalar ILP (R10: 197) and 2-chain ILP (R11: 206 + scratch spill) both lose
//  - pk f32 is dual-pass on gfx950 (R5); early-exit ~never fires (R6) but is
//    exact and free, kept.
// Structure: gc refreshed every 4 steps, -gc*hw pre-folded into both
// kink-branch constants; kink test + box clip exact per step.

#define XLO -10.0f
#define XHI 10.0f

typedef float v2 __attribute__((ext_vector_type(2)));

__device__ __forceinline__ v2 fma2(v2 a, v2 b, v2 c) {
    return __builtin_elementwise_fma(a, b, c);
}

__device__ __forceinline__ float clampx(float x) {
    return fminf(fmaxf(x, XLO), XHI);   // v_med3_f32
}

__device__ __forceinline__ v2 clamp2(v2 x) {
    v2 r;
    r.x = clampx(x.x);
    r.y = clampx(x.y);
    return r;
}

__device__ __forceinline__ float rsq_nr(float t) {
    float y = __builtin_amdgcn_rsqf(t);
    float c = __builtin_fmaf(-0.5f * (t * y), y, 1.5f);
    return y * c;
}

struct P {
    v2 w0s, w1s, v0s, v1s, bm1s, hw0s, hw1s, mvr;
};

// nblocks blocks of 4 PGA steps; gc refreshed per block, pre-folded into the
// kink-branch constants f*/f*k. Kink test + clip exact per step.
__device__ __forceinline__ void solve(int nblocks, v2 sx0, v2 sx1,
                                      v2 e0, v2 e1, v2 e0k, v2 e1k,
                                      const P& p, v2& ox0, v2& ox1) {
    const v2 c95 = 0.95f, one = 1.0f;
    v2 x0 = sx0, x1 = sx1;
    for (int k = 0; k < nblocks; ++k) {
        v2 tau = fma2(x0, p.w0s, fma2(x1, p.w1s, p.bm1s));
        v2 t2 = fma2(tau, tau, one);
        v2 rq;
        rq.x = __builtin_amdgcn_rsqf(t2.x);
        rq.y = __builtin_amdgcn_rsqf(t2.y);
        v2 gc = tau * rq;
        v2 f0  = fma2(-gc, p.hw0s, e0);    // no-kink branch const, gc folded
        v2 f0k = fma2(-gc, p.hw0s, e0k);   // kink branch const
        v2 f1  = fma2(-gc, p.hw1s, e1);
        v2 f1k = fma2(-gc, p.hw1s, e1k);
#pragma unroll
        for (int h = 0; h < 4; ++h) {
            v2 q = fma2(x0, p.v0s, fma2(x1, p.v1s, p.mvr));
            v2 a0, a1;
            a0.x = (q.x > 0.0f) ? f0k.x : f0.x;
            a0.y = (q.y > 0.0f) ? f0k.y : f0.y;
            a1.x = (q.x > 0.0f) ? f1k.x : f1.x;
            a1.y = (q.y > 0.0f) ? f1k.y : f1.y;
            x0 = clamp2(fma2(c95, x0, a0));
            x1 = clamp2(fma2(c95, x1, a1));
        }
    }
    ox0 = x0;
    ox1 = x1;
}

__global__ __launch_bounds__(256, 8)
void strategic_kernel(const float* __restrict__ X,
                      const float* __restrict__ wp,
                      const float* __restrict__ bp,
                      const float* __restrict__ vp,
                      float* __restrict__ out, int B2) {
    int i = blockIdx.x * blockDim.x + threadIdx.x;
    if (i >= B2) return;

    const float w0 = wp[0], w1 = wp[1], b = bp[0], v0 = vp[0], v1 = vp[1];

    P p;
    p.w0s = w0; p.w1s = w1; p.v0s = v0; p.v1s = v1;
    p.bm1s = b - 1.0f;
    p.hw0s = 0.5f * w0; p.hw1s = 0.5f * w1;
    const v2 bp1s = b + 1.0f;
    const v2 k0s = 0.475f * v0, k1s = 0.475f * v1;   // COST*(1-EPS)*v
    const v2 one = 1.0f, half = 0.5f, c05 = 0.05f;

    // Samples 2i and 2i+1 packed into v2 lanes.
    float4 r4 = reinterpret_cast<const float4*>(X)[i];
    v2 r0, r1;
    r0.x = r4.x; r0.y = r4.z;   // coord 0 of both samples
    r1.x = r4.y; r1.y = r4.w;   // coord 1 of both samples

    const v2 sx0 = clamp2(r0), sx1 = clamp2(r1);        // inner-solve start
    p.mvr.x = -(__builtin_fmaf(r1.x, v1, r0.x * v0));
    p.mvr.y = -(__builtin_fmaf(r1.y, v1, r0.y * v0));
    const v2 p5r0 = c05 * r0, p5r1 = c05 * r1;          // 0.05*r
    v2 xt0 = r0, xt1 = r1;                              // CCP state

    // fd history for exact cycle detection (NaN never compares equal)
    v2 fc_p1 = __builtin_nanf(""), fc_p2 = __builtin_nanf("");
    v2 e0, e1, e0k, e1k;

    int c = 0;
    for (; c < 11; ++c) {
        // fder at xt (NR-refined rsq; 11 calls, cheap)
        v2 sp = fma2(xt0, p.w0s, fma2(xt1, p.w1s, bp1s));
        v2 tt = fma2(sp, sp, one);
        v2 rs;
        rs.x = rsq_nr(tt.x);
        rs.y = rsq_nr(tt.y);
        v2 fc = half * sp * rs;
        e0 = fma2(fc, p.w0s, p5r0);
        e1 = fma2(fc, p.w1s, p5r1);
        e0k = e0 - k0s;
        e1k = e1 - k1s;

        bool per1 = (fc.x == fc_p1.x) && (fc.y == fc_p1.y);
        bool per2 = (fc.x == fc_p2.x) && (fc.y == fc_p2.y);
        if (__all(per1) || (__all(per2) && ((10 - c) & 1))) break;
        fc_p2 = fc_p1;
        fc_p1 = fc;

        solve(25, sx0, sx1, e0, e1, e0k, e1k, p, xt0, xt1);  // 100 steps
    }

    if (c == 11) {   // natural exhaust: e-consts are fd(S_9); refresh at S_10
        v2 sp = fma2(xt0, p.w0s, fma2(xt1, p.w1s, bp1s));
        v2 tt = fma2(sp, sp, one);
        v2 rs;
        rs.x = rsq_nr(tt.x);
        rs.y = rsq_nr(tt.y);
        v2 fc = half * sp * rs;
        e0 = fma2(fc, p.w0s, p5r0);
        e1 = fma2(fc, p.w1s, p5r1);
        e0k = e0 - k0s;
        e1k = e1 - k1s;
    }

    // Final (differentiable) solve: 200 steps = 50 blocks
    v2 x0, x1;
    solve(50, sx0, sx1, e0, e1, e0k, e1k, p, x0, x1);

    v2 bs = b;
    v2 res = fma2(x0, p.w0s, fma2(x1, p.w1s, bs));
    float2 o;
    o.x = res.x;
    o.y = res.y;
    reinterpret_cast<float2*>(out)[i] = o;
}

extern "C" void kernel_launch(void* const* d_in, const int* in_sizes, int n_in,
                              void* d_out, int out_size, void* d_ws, size_t ws_size,
                              hipStream_t stream) {
    const float* X = (const float*)d_in[0];
    const float* w = (const float*)d_in[1];
    const float* b = (const float*)d_in[2];
    const float* v = (const float*)d_in[3];
    float* out = (float*)d_out;

    int B = in_sizes[0] / 2;   // X is [B, 2]
    int B2 = B / 2;            // 2 samples per thread (packed)
    int block = 256;
    int grid = (B2 + block - 1) / block;
    strategic_kernel<<<grid, block, 0, stream>>>(X, w, b, v, out, B2);
}